// Round 2
// baseline (3535.878 us; speedup 1.0000x reference)
//
#include <hip/hip_runtime.h>
#include <hip/hip_bf16.h>

#define LYR  6
#define BATCH 2
#define TOK  64
#define SEQ  1024
#define EMB  768
#define HEADS 12
#define HDK  64
#define DFF  3072

typedef __bf16 bf16_t;
typedef __bf16 bf16x8 __attribute__((ext_vector_type(8)));
typedef float  f32x4  __attribute__((ext_vector_type(4)));

static __device__ __forceinline__ unsigned short bfbits(float f) {
    bf16_t b = (bf16_t)f; return *(unsigned short*)&b;
}
static __device__ __forceinline__ float loadf(const void* p, size_t e, int f32) {
    if (f32) return ((const float*)p)[e];
    return (float)((const bf16_t*)p)[e];
}
static __device__ __forceinline__ ushort4 load4bf(const void* p, size_t e, int f32) {
    if (f32) {
        float4 f = *(const float4*)((const float*)p + e);
        ushort4 u; u.x = bfbits(f.x); u.y = bfbits(f.y); u.z = bfbits(f.z); u.w = bfbits(f.w);
        return u;
    }
    return *(const ushort4*)((const unsigned short*)p + e);
}

// ---------------------------------------------------------------------------
// dtype detector: scan first 4096 16-bit chunks of Wq as bf16.
// bf16 data (std 0.02) -> |v| < 1 everywhere.  fp32 data -> mantissa halves
// decode as huge/NaN bf16 with ~25% probability.  flag: 1 = fp32, 0 = bf16.
// ---------------------------------------------------------------------------
__global__ __launch_bounds__(256)
void detect_k(const void* w, int* flag)
{
    __shared__ int bad;
    if (threadIdx.x == 0) bad = 0;
    __syncthreads();
    const unsigned short* p = (const unsigned short*)w;
    int local = 0;
    for (int i = threadIdx.x; i < 4096; i += 256) {
        float v = (float)(*(const bf16_t*)&p[i]);
        if (!(v < 1e3f && v > -1e3f)) local = 1;   // catches NaN too
    }
    if (local) atomicOr(&bad, 1);
    __syncthreads();
    if (threadIdx.x == 0) *flag = bad;
}

// ---------------------------------------------------------------------------
// Generic 64x64-tile MFMA GEMM.  C = A * B (fp32 accumulate), bf16 MFMA.
//   BTRANS=false: B is [K,N]; BTRANS=true: B is [N,K] (computes A*B^T)
//   AF32: A operand is fp32 in memory (converted to bf16 while staging)
//   bf32p: if non-null and *bf32p==1, B operand is fp32 in memory
//   boff0: flat ELEMENT offset added to B (layer offset for weights)
// EPI: 0 = bf16 store, 1 = bf16 relu, 2 = fp32, 3 = fp32 *scale + mask(-1e9)
// ---------------------------------------------------------------------------
template<int EPI, bool BTRANS, bool AF32>
__global__ __launch_bounds__(256)
void gemm_k(const void* __restrict__ Aall, long lda, long sAb, long sAh,
            const void* __restrict__ Ball, long ldb, long boff0, long sBb, long sBh,
            void* __restrict__ Call, long ldc, long sCb, long sCh,
            int K, float scale, const int* __restrict__ pad,
            const int* __restrict__ bf32p)
{
    __shared__ __align__(16) unsigned short As[64][40];
    __shared__ __align__(16) unsigned short Bs[64][40];   // stored [n][k]

    const int bF32 = bf32p ? *bf32p : 0;
    const int z  = blockIdx.z;
    const int bq = z / HEADS, hq = z % HEADS;
    const size_t aoff = (size_t)bq * sAb + (size_t)hq * sAh;
    const size_t boff = (size_t)boff0 + (size_t)bq * sBb + (size_t)hq * sBh;
    const size_t coff = (size_t)bq * sCb + (size_t)hq * sCh;

    const int tid  = threadIdx.x;
    const int lane = tid & 63;
    const int wave = tid >> 6;
    const int bm = blockIdx.x * 64;
    const int bn = blockIdx.y * 64;

    f32x4 acc[4];
#pragma unroll
    for (int t = 0; t < 4; t++) acc[t] = (f32x4){0.f, 0.f, 0.f, 0.f};

    for (int k0 = 0; k0 < K; k0 += 32) {
#pragma unroll
        for (int i = 0; i < 2; i++) {
            int e = (tid + i * 256) * 4;
            int r = e >> 5, c = e & 31;
            ushort4 u = load4bf(Aall, aoff + (size_t)(bm + r) * lda + k0 + c, AF32 ? 1 : 0);
            *(ushort4*)&As[r][c] = u;
        }
        if (BTRANS) {
#pragma unroll
            for (int i = 0; i < 2; i++) {
                int e = (tid + i * 256) * 4;
                int r = e >> 5, c = e & 31;
                ushort4 u = load4bf(Ball, boff + (size_t)(bn + r) * ldb + k0 + c, bF32);
                *(ushort4*)&Bs[r][c] = u;
            }
        } else {
#pragma unroll
            for (int i = 0; i < 2; i++) {
                int e = (tid + i * 256) * 4;
                int kk = e >> 6, n = e & 63;
                ushort4 u = load4bf(Ball, boff + (size_t)(k0 + kk) * ldb + bn + n, bF32);
                Bs[n + 0][kk] = u.x; Bs[n + 1][kk] = u.y;
                Bs[n + 2][kk] = u.z; Bs[n + 3][kk] = u.w;
            }
        }
        __syncthreads();

        const int mrow = wave * 16 + (lane & 15);
        const int kq   = (lane >> 4) * 8;
        bf16x8 av = *(const bf16x8*)&As[mrow][kq];
#pragma unroll
        for (int t = 0; t < 4; t++) {
            bf16x8 bv = *(const bf16x8*)&Bs[t * 16 + (lane & 15)][kq];
            acc[t] = __builtin_amdgcn_mfma_f32_16x16x32_bf16(av, bv, acc[t], 0, 0, 0);
        }
        __syncthreads();
    }

    const int colb = bn + (lane & 15);
    const int rowb = bm + wave * 16 + ((lane >> 4) << 2);
#pragma unroll
    for (int t = 0; t < 4; t++) {
        const int col = colb + t * 16;
#pragma unroll
        for (int r = 0; r < 4; r++) {
            const int row = rowb + r;
            float v = acc[t][r];
            size_t idx = coff + (size_t)row * ldc + col;
            if constexpr (EPI == 0) {
                ((bf16_t*)Call)[idx] = (bf16_t)v;
            } else if constexpr (EPI == 1) {
                ((bf16_t*)Call)[idx] = (bf16_t)(v > 0.f ? v : 0.f);
            } else if constexpr (EPI == 2) {
                ((float*)Call)[idx] = v;
            } else {
                v *= scale;
                if (col > row || pad[bq * SEQ + col]) v = -1e9f;
                ((float*)Call)[idx] = v;
            }
        }
    }
}

__global__ __launch_bounds__(256)
void posadd_k(const void* __restrict__ x, const void* __restrict__ tp,
              const void* __restrict__ sp, float* __restrict__ X,
              bf16_t* __restrict__ XB, int* __restrict__ pad,
              const int* __restrict__ flagp)
{
    const int f32 = *flagp;
    const int row = blockIdx.x;              // b*S + s
    const int s = row % SEQ;
    const int f = s / TOK, tt = s % TOK;
    const int tid = threadIdx.x;
#pragma unroll
    for (int i = 0; i < 3; i++) {
        int e = tid + i * 256;
        float v = loadf(x, (size_t)row * EMB + e, f32)
                + loadf(tp, (size_t)f * EMB + e, f32)
                + loadf(sp, (size_t)tt * EMB + e, f32);
        X[(size_t)row * EMB + e]  = v;
        XB[(size_t)row * EMB + e] = (bf16_t)v;
        if (e == 0) pad[row] = (v == 0.0f) ? 1 : 0;
    }
}

__global__ __launch_bounds__(256)
void softmax_k(float* __restrict__ sc, void* __restrict__ outp, long ooff,
               const int* __restrict__ flagp)
{
    const int f32 = *flagp;
    const int row = blockIdx.x;
    float* srow = sc + (size_t)row * SEQ;
    const int tid = threadIdx.x;
    float4 v = ((const float4*)srow)[tid];
    __shared__ float red[4];

    float m = fmaxf(fmaxf(v.x, v.y), fmaxf(v.z, v.w));
#pragma unroll
    for (int off = 32; off; off >>= 1) m = fmaxf(m, __shfl_down(m, off, 64));
    if ((tid & 63) == 0) red[tid >> 6] = m;
    __syncthreads();
    m = fmaxf(fmaxf(red[0], red[1]), fmaxf(red[2], red[3]));
    __syncthreads();

    float e0 = __expf(v.x - m), e1 = __expf(v.y - m);
    float e2 = __expf(v.z - m), e3 = __expf(v.w - m);
    float s = e0 + e1 + e2 + e3;
#pragma unroll
    for (int off = 32; off; off >>= 1) s += __shfl_down(s, off, 64);
    if ((tid & 63) == 0) red[tid >> 6] = s;
    __syncthreads();
    s = red[0] + red[1] + red[2] + red[3];
    float inv = 1.0f / s;
    float4 p; p.x = e0 * inv; p.y = e1 * inv; p.z = e2 * inv; p.w = e3 * inv;

    ((float4*)srow)[tid] = p;                       // in-place: PV GEMM input
    const size_t o = (size_t)ooff + (size_t)row * SEQ;
    if (f32) {
        ((float4*)((float*)outp + o))[tid] = p;
    } else {
        ushort4 u; u.x = bfbits(p.x); u.y = bfbits(p.y);
        u.z = bfbits(p.z); u.w = bfbits(p.w);
        ((ushort4*)((unsigned short*)outp + o))[tid] = u;
    }
}

static __device__ __forceinline__ float bsum(float v, float* red)
{
#pragma unroll
    for (int off = 32; off; off >>= 1) v += __shfl_down(v, off, 64);
    const int lane = threadIdx.x & 63, w = threadIdx.x >> 6;
    __syncthreads();
    if (lane == 0) red[w] = v;
    __syncthreads();
    return red[0] + red[1] + red[2] + red[3];
}

__global__ __launch_bounds__(256)
void ln_k(const float* __restrict__ proj, float* __restrict__ X,
          bf16_t* __restrict__ XB, const void* __restrict__ g, long goff,
          const void* __restrict__ bb, long boff2, const int* __restrict__ flagp)
{
    const int f32 = *flagp;
    const int row = blockIdx.x;
    const float* p = proj + (size_t)row * EMB;
    float* x  = X  + (size_t)row * EMB;
    bf16_t* xb = XB + (size_t)row * EMB;
    const int tid = threadIdx.x;
    __shared__ float red[4];

    float v[3];
    float sum = 0.f;
#pragma unroll
    for (int i = 0; i < 3; i++) { int e = tid + i * 256; v[i] = p[e] + x[e]; sum += v[i]; }
    sum = bsum(sum, red);
    const float mean = sum * (1.0f / EMB);

    float vs = 0.f;
#pragma unroll
    for (int i = 0; i < 3; i++) { float d = v[i] - mean; vs += d * d; }
    vs = bsum(vs, red);
    const float rstd = rsqrtf(vs * (1.0f / EMB) + 1e-5f);

#pragma unroll
    for (int i = 0; i < 3; i++) {
        int e = tid + i * 256;
        float y = (v[i] - mean) * rstd * loadf(g, goff + e, f32) + loadf(bb, boff2 + e, f32);
        x[e] = y;
        xb[e] = (bf16_t)y;
    }
}

__global__ __launch_bounds__(256)
void copyout_k(const float* __restrict__ X, void* __restrict__ outp,
               const int* __restrict__ flagp)
{
    const int f32 = *flagp;
    int i = blockIdx.x * 256 + threadIdx.x;
    float v = X[i];
    if (f32) ((float*)outp)[i] = v;
    else     ((bf16_t*)outp)[i] = (bf16_t)v;
}

// ---------------------------------------------------------------------------
extern "C" void kernel_launch(void* const* d_in, const int* in_sizes, int n_in,
                              void* d_out, int out_size, void* d_ws, size_t ws_size,
                              hipStream_t stream)
{
    const void* x  = d_in[0];
    const void* tp = d_in[1];
    const void* sp = d_in[2];
    const void* Wq = d_in[3];
    const void* Wk = d_in[4];
    const void* Wv = d_in[5];
    const void* Wo = d_in[6];
    const void* g1 = d_in[7];
    const void* b1 = d_in[8];
    const void* W1 = d_in[9];
    const void* W2 = d_in[10];
    const void* g2 = d_in[11];
    const void* b2 = d_in[12];

    const size_t BS   = (size_t)BATCH * SEQ;                 // 2048
    const size_t BSE  = BS * EMB;                             // 1.57M
    const size_t ATT1 = (size_t)BATCH * HEADS * SEQ * SEQ;    // 25.2M / layer

    char* ws = (char*)d_ws;
    size_t off = 0;
    auto alloc = [&](size_t bytes) { void* p = ws + off; off += (bytes + 255) & ~255ULL; return p; };

    float*  X    = (float*)alloc(BSE * 4);
    bf16_t* XB   = (bf16_t*)alloc(BSE * 2);
    bf16_t* QB   = (bf16_t*)alloc(BSE * 2);
    bf16_t* KB   = (bf16_t*)alloc(BSE * 2);
    bf16_t* VB   = (bf16_t*)alloc(BSE * 2);
    bf16_t* CTXB = (bf16_t*)alloc(BSE * 2);
    bf16_t* HB   = (bf16_t*)alloc(BS * DFF * 2);
    float*  PRJ  = (float*)alloc(BSE * 4);
    float*  SC   = (float*)alloc(ATT1 * 4);
    int*    pad  = (int*)alloc(BS * 4);
    int*    flag = (int*)alloc(256);

    detect_k<<<dim3(1), 256, 0, stream>>>(Wq, flag);
    posadd_k<<<dim3((int)BS), 256, 0, stream>>>(x, tp, sp, X, XB, pad, flag);

    for (int l = 0; l < LYR; l++) {
        const long oW  = (long)l * EMB * EMB;
        const long oF1 = (long)l * EMB * DFF;
        const long oF2 = (long)l * DFF * EMB;
        const long oLN = (long)l * EMB;
        const long probs_off = (long)(BSE + (size_t)l * ATT1);

        // QKV projections: [2048,768] x [768,768] -> bf16
        gemm_k<0, false, false><<<dim3(32, 12, 1), 256, 0, stream>>>(
            XB, EMB, 0, 0, Wq, EMB, oW, 0, 0, QB, EMB, 0, 0, EMB, 0.f, nullptr, flag);
        gemm_k<0, false, false><<<dim3(32, 12, 1), 256, 0, stream>>>(
            XB, EMB, 0, 0, Wk, EMB, oW, 0, 0, KB, EMB, 0, 0, EMB, 0.f, nullptr, flag);
        gemm_k<0, false, false><<<dim3(32, 12, 1), 256, 0, stream>>>(
            XB, EMB, 0, 0, Wv, EMB, oW, 0, 0, VB, EMB, 0, 0, EMB, 0.f, nullptr, flag);

        // scores = scale * Q K^T + mask -> fp32 SC  (per b,h)
        gemm_k<3, true, false><<<dim3(16, 16, BATCH * HEADS), 256, 0, stream>>>(
            QB, EMB, (long)SEQ * EMB, HDK,
            KB, EMB, 0, (long)SEQ * EMB, HDK,
            SC, SEQ, (long)HEADS * SEQ * SEQ, (long)SEQ * SEQ,
            HDK, 0.125f, pad, nullptr);

        // softmax -> probs (fp32 in-place in SC) + dtype-branched d_out
        softmax_k<<<dim3(BATCH * HEADS * SEQ), 256, 0, stream>>>(SC, d_out, probs_off, flag);

        // ctx = P V  (A = fp32 probs): [1024,1024] x [1024,64] -> bf16 CTXB
        gemm_k<0, false, true><<<dim3(16, 1, BATCH * HEADS), 256, 0, stream>>>(
            SC, SEQ, (long)HEADS * SEQ * SEQ, (long)SEQ * SEQ,
            VB, EMB, 0, (long)SEQ * EMB, HDK,
            CTXB, EMB, (long)SEQ * EMB, HDK,
            SEQ, 0.f, nullptr, nullptr);

        // attn out projection -> fp32 PRJ, then LN1
        gemm_k<2, false, false><<<dim3(32, 12, 1), 256, 0, stream>>>(
            CTXB, EMB, 0, 0, Wo, EMB, oW, 0, 0, PRJ, EMB, 0, 0, EMB, 0.f, nullptr, flag);
        ln_k<<<dim3((int)BS), 256, 0, stream>>>(PRJ, X, XB, g1, oLN, b1, oLN, flag);

        // FFN: relu(X W1) W2, then LN2
        gemm_k<1, false, false><<<dim3(32, 48, 1), 256, 0, stream>>>(
            XB, EMB, 0, 0, W1, DFF, oF1, 0, 0, HB, DFF, 0, 0, EMB, 0.f, nullptr, flag);
        gemm_k<2, false, false><<<dim3(32, 12, 1), 256, 0, stream>>>(
            HB, DFF, 0, 0, W2, EMB, oF2, 0, 0, PRJ, EMB, 0, 0, DFF, 0.f, nullptr, flag);
        ln_k<<<dim3((int)BS), 256, 0, stream>>>(PRJ, X, XB, g2, oLN, b2, oLN, flag);
    }

    copyout_k<<<dim3((int)(BSE / 256)), 256, 0, stream>>>(X, d_out, flag);
}